// Round 3
// baseline (113.492 us; speedup 1.0000x reference)
//
#include <hip/hip_runtime.h>
#include <hip/hip_bf16.h>

#define B_   4
#define C_   64
#define N_   16384
#define K_   20
#define S_   10
#define OUT_ 64
#define CH_  128
#define ROWS_ (B_ * N_)

typedef __attribute__((ext_vector_type(4))) float  f32x4;
typedef __attribute__((ext_vector_type(8))) __bf16 bf16x8;
typedef __attribute__((ext_vector_type(4))) __bf16 bf16x4;
typedef __attribute__((ext_vector_type(4))) unsigned short u16x4;

__device__ inline float bf2f(unsigned short u) {
  union { unsigned int i; float f; } x; x.i = ((unsigned int)u) << 16; return x.f;
}
__device__ inline float bflo(unsigned int u) {
  union { unsigned int i; float f; } x; x.i = u << 16; return x.f;
}
__device__ inline float bfhi(unsigned int u) {
  union { unsigned int i; float f; } x; x.i = u & 0xffff0000u; return x.f;
}

// ---- fused: transpose (B,C,N) f32 -> (B*N,C) bf16  |  top-S sample  |  stats zero ----
// blocks [0,4096): transpose tiles; blocks [4096,4352): sampling (block 4096 also zeroes stats)
__global__ __launch_bounds__(256) void k_prep(
    const float* __restrict__ x, __bf16* __restrict__ xt,
    const float* __restrict__ scores, const int* __restrict__ idxmat,
    int* __restrict__ sampled, float* __restrict__ stats) {
  const int bid = blockIdx.x;
  const int t   = threadIdx.x;
  if (bid < 4096) {
    __shared__ float tile[32][33];   // [c_local][n_local]
    const int nt = bid & 511, ct = (bid >> 9) & 1, b = bid >> 10;
    const int n0 = nt * 32, c0 = ct * 32;
    const int tx = t & 31, ty = t >> 5;
#pragma unroll
    for (int k = 0; k < 32; k += 8)
      tile[ty + k][tx] = x[((size_t)(b * C_ + c0 + ty + k)) * N_ + n0 + tx];
    __syncthreads();
    const int nl = t >> 3;           // 0..31 (n)
    const int cb = (t & 7) * 4;      // 0..28 (c)
    bf16x4 p;
#pragma unroll
    for (int i = 0; i < 4; ++i) p[i] = (__bf16)tile[cb + i][nl];
    *(bf16x4*)&xt[((size_t)(b * N_ + n0 + nl)) * C_ + c0 + cb] = p;
  } else {
    if (bid == 4096) stats[t] = 0.f;
    const int j = (bid - 4096) * 256 + t;
    const float* sc = scores + (size_t)j * K_;
    const int*   id = idxmat + (size_t)j * K_;
    float sv[K_]; int iv[K_];
#pragma unroll
    for (int k = 0; k < K_; ++k) { sv[k] = sc[k]; iv[k] = id[k]; }
    int* outp = sampled + (size_t)j * S_;
#pragma unroll
    for (int k = 0; k < K_; ++k) {
      const float sk = sv[k];
      int rank = 0;
#pragma unroll
      for (int m = 0; m < K_; ++m)
        rank += ((sv[m] > sk) || (sv[m] == sk && m < k)) ? 1 : 0;
      if (rank < S_) outp[rank] = iv[k];
    }
  }
}

// ---------------- BN stats: per-channel sums (bf16 xt) ----------------
// stats: [0:64)=sum_d  [64:128)=sumsq_d  [128:192)=sum_cen  [192:256)=sumsq_cen
__global__ __launch_bounds__(256) void k_stats(const unsigned int* __restrict__ xtu,
                                               const int* __restrict__ sampled,
                                               float* __restrict__ stats) {
  const int t    = threadIdx.x;
  const int half = (blockIdx.x * 256 + t) >> 5;   // global half-wave id
  const int cp   = t & 31;                        // channel pair 0..31
  const int nh   = gridDim.x * 8;
  float sd0 = 0, sd1 = 0, qd0 = 0, qd1 = 0, sc0 = 0, sc1 = 0, qc0 = 0, qc1 = 0;
  for (int j = half; j < ROWS_; j += nh) {
    const unsigned int cu = xtu[(size_t)j * 32 + cp];
    const float c0 = bflo(cu), c1 = bfhi(cu);
    sc0 += c0; sc1 += c1; qc0 += c0 * c0; qc1 += c1 * c1;
    const int* sp = sampled + (size_t)j * S_;
#pragma unroll
    for (int s = 0; s < S_; ++s) {
      const int nb = sp[s];
      const unsigned int vu = xtu[(size_t)nb * 32 + cp];
      const float d0 = bflo(vu) - c0;
      const float d1 = bfhi(vu) - c1;
      sd0 += d0; qd0 += d0 * d0; sd1 += d1; qd1 += d1 * d1;
    }
  }
  __shared__ float sred[256];
  sred[t] = 0.f;
  __syncthreads();
  const int c0i = 2 * cp;
  atomicAdd(&sred[c0i], sd0);        atomicAdd(&sred[c0i + 1], sd1);
  atomicAdd(&sred[64 + c0i], qd0);   atomicAdd(&sred[64 + c0i + 1], qd1);
  atomicAdd(&sred[128 + c0i], sc0);  atomicAdd(&sred[128 + c0i + 1], sc1);
  atomicAdd(&sred[192 + c0i], qc0);  atomicAdd(&sred[192 + c0i + 1], qc1);
  __syncthreads();
  atomicAdd(&stats[t], sred[t]);
}

// ---------------- main: inline BN-fold + act + split pointwise MFMA + max over S ----------------
__global__ __launch_bounds__(256) void k_main(
    const __bf16* __restrict__ xt, const int* __restrict__ sampled,
    const float* __restrict__ stats, const float* __restrict__ dww,
    const float* __restrict__ gamma, const float* __restrict__ beta,
    const float* __restrict__ pw, float* __restrict__ out) {
  __shared__ __bf16 dact[160 * 64];   // rows (s*16+r), 128B each, XOR-swizzled
  __shared__ __bf16 cact[16 * 64];    // central act rows
  __shared__ float  ost[16][68];      // output staging; front 256 floats alias ABs

  float* ABs = &ost[0][0];            // [0:128)=A, [128:256)=Bc

  const int t    = threadIdx.x;
  const int lane = t & 63;
  const int w    = t >> 6;            // wave -> output cols [16w,16w+16)
  const int j0   = blockIdx.x * 16;
  const int b    = j0 / N_;
  const int n0   = j0 % N_;
  const int r    = t >> 4;            // row 0..15
  const int q    = t & 15;            // channel quad

  // fold BN into per-channel affine (was k_finalize)
  if (t < CH_) {
    float mean_e, var_e;
    if (t < C_) {
      const float cnt = (float)ROWS_ * (float)S_;
      const float su = stats[t], sq = stats[64 + t];
      mean_e = su / cnt; var_e = sq / cnt - mean_e * mean_e;
    } else {
      const float cnt = (float)ROWS_;
      const float su = stats[128 + (t - C_)], sq = stats[192 + (t - C_)];
      mean_e = su / cnt; var_e = sq / cnt - mean_e * mean_e;
    }
    const float wg = dww[t], g = gamma[t];
    const float inv = rsqrtf(wg * wg * var_e + 1e-5f);
    ABs[t]       = wg * g * inv;
    ABs[CH_ + t] = beta[t] - wg * mean_e * inv * g;
  }
  __syncthreads();

  const f32x4 a_d = *(const f32x4*)&ABs[4 * q];
  const f32x4 a_c = *(const f32x4*)&ABs[C_ + 4 * q];
  const f32x4 b_d = *(const f32x4*)&ABs[CH_ + 4 * q];
  const f32x4 b_c = *(const f32x4*)&ABs[CH_ + C_ + 4 * q];

  // central load + c-act (channels 64..127 of edge)
  float cen[4];
  {
    u16x4 cu = *(const u16x4*)&xt[(size_t)(j0 + r) * C_ + 4 * q];
    bf16x4 p;
#pragma unroll
    for (int i = 0; i < 4; ++i) {
      cen[i] = bf2f(cu[i]);
      const float tt = a_c[i] * cen[i] + b_c[i];
      p[i] = (__bf16)fmaxf(tt, 0.2f * tt);
    }
    const int byt = r * 128 + ((8 * q) ^ ((r & 7) << 4));
    *(bf16x4*)((char*)cact + byt) = p;
  }

  // all S neighbor gathers + d-act (channels 0..63 of edge)
  const int* sp = sampled + (size_t)(j0 + r) * S_;
#pragma unroll
  for (int s = 0; s < S_; ++s) {
    const int nb = sp[s];
    u16x4 vu = *(const u16x4*)&xt[(size_t)nb * C_ + 4 * q];
    bf16x4 p;
#pragma unroll
    for (int i = 0; i < 4; ++i) {
      const float d  = bf2f(vu[i]) - cen[i];
      const float tt = a_d[i] * d + b_d[i];
      p[i] = (__bf16)fmaxf(tt, 0.2f * tt);
    }
    const int row = s * 16 + r;
    const int byt = row * 128 + ((8 * q) ^ ((r & 7) << 4));  // (row&7)==(r&7)
    *(bf16x4*)((char*)dact + byt) = p;
  }

  // B-fragments: pw^T; d-part K=[0,64), c-part K=[64,128)
  bf16x8 bfd[2], bfc[2];
  {
    const int o  = 16 * w + (lane & 15);
    const int kb = 8 * (lane >> 4);
#pragma unroll
    for (int ts = 0; ts < 2; ++ts) {
      const int k = 32 * ts + kb;
      f32x4 v0 = *(const f32x4*)&pw[(size_t)o * CH_ + k];
      f32x4 v1 = *(const f32x4*)&pw[(size_t)o * CH_ + k + 4];
      f32x4 w0 = *(const f32x4*)&pw[(size_t)o * CH_ + C_ + k];
      f32x4 w1 = *(const f32x4*)&pw[(size_t)o * CH_ + C_ + k + 4];
      bf16x8 f, g;
#pragma unroll
      for (int i = 0; i < 4; ++i) {
        f[i] = (__bf16)v0[i]; f[4 + i] = (__bf16)v1[i];
        g[i] = (__bf16)w0[i]; g[4 + i] = (__bf16)w1[i];
      }
      bfd[ts] = f; bfc[ts] = g;
    }
  }

  __syncthreads();

  const int arow  = lane & 15;
  const int akoff = 16 * (lane >> 4);
  const int swz   = (arow & 7) << 4;

  f32x4 cacc = {0.f, 0.f, 0.f, 0.f};
#pragma unroll
  for (int ts = 0; ts < 2; ++ts) {
    bf16x8 a = *(bf16x8*)((char*)cact + arow * 128 + ((64 * ts + akoff) ^ swz));
    cacc = __builtin_amdgcn_mfma_f32_16x16x32_bf16(a, bfc[ts], cacc, 0, 0, 0);
  }

  f32x4 rmax;
  rmax[0] = rmax[1] = rmax[2] = rmax[3] = -__builtin_inff();
#pragma unroll
  for (int s = 0; s < S_; ++s) {
    f32x4 acc = {0.f, 0.f, 0.f, 0.f};
#pragma unroll
    for (int ts = 0; ts < 2; ++ts) {
      bf16x8 a = *(bf16x8*)((char*)dact + (s * 16 + arow) * 128 + ((64 * ts + akoff) ^ swz));
      acc = __builtin_amdgcn_mfma_f32_16x16x32_bf16(a, bfd[ts], acc, 0, 0, 0);
    }
#pragma unroll
    for (int i = 0; i < 4; ++i) rmax[i] = fmaxf(rmax[i], acc[i]);
  }

  __syncthreads();   // ABs (aliased on ost) fully consumed before staging writes
  { // stage: C/D mapping col=lane&15, row=4*(lane>>4)+i
    const int ol = lane & 15;
    const int rb = 4 * (lane >> 4);
#pragma unroll
    for (int i = 0; i < 4; ++i) ost[rb + i][16 * w + ol] = rmax[i] + cacc[i];
  }
  __syncthreads();
  { // coalesced store: out[b][o][n0..n0+15]
    const int o  = t >> 2;
    const int sg = t & 3;
    f32x4 v;
#pragma unroll
    for (int i = 0; i < 4; ++i) v[i] = ost[sg * 4 + i][o];
    *(f32x4*)&out[((size_t)(b * OUT_ + o)) * N_ + n0 + sg * 4] = v;
  }
}

extern "C" void kernel_launch(void* const* d_in, const int* in_sizes, int n_in,
                              void* d_out, int out_size, void* d_ws, size_t ws_size,
                              hipStream_t stream) {
  const float* x      = (const float*)d_in[0];
  const int*   cif    = (const int*)  d_in[1];
  const float* scores = (const float*)d_in[2];
  const float* dww    = (const float*)d_in[3];
  const float* pw     = (const float*)d_in[4];
  const float* gamma  = (const float*)d_in[5];
  const float* beta   = (const float*)d_in[6];
  float* out = (float*)d_out;

  char* ws = (char*)d_ws;
  __bf16* xt      = (__bf16*)(ws);                            //  8,388,608 B
  int*    sampled = (int*)   (ws + 8388608);                  //  2,621,440 B
  float*  stats   = (float*) (ws + 8388608 + 2621440);        //      1,024 B

  k_prep<<<4096 + 256, 256, 0, stream>>>(x, xt, scores, cif, sampled, stats);
  k_stats<<<2048, 256, 0, stream>>>((const unsigned int*)xt, sampled, stats);
  k_main<<<ROWS_ / 16, 256, 0, stream>>>(xt, sampled, stats, dww, gamma, beta, pw, out);
}

// Round 4
// 74.775 us; speedup vs baseline: 1.5178x; 1.5178x over previous
//
#include <hip/hip_runtime.h>
#include <hip/hip_bf16.h>

#define B_   4
#define C_   64
#define N_   16384
#define K_   20
#define S_   10
#define OUT_ 64
#define CH_  128
#define ROWS_ (B_ * N_)
#define RST_ 16   // stats replicas

typedef __attribute__((ext_vector_type(4))) float  f32x4;
typedef __attribute__((ext_vector_type(8))) __bf16 bf16x8;
typedef __attribute__((ext_vector_type(4))) __bf16 bf16x4;
typedef __attribute__((ext_vector_type(4))) unsigned short u16x4;

__device__ inline float bf2f(unsigned short u) {
  union { unsigned int i; float f; } x; x.i = ((unsigned int)u) << 16; return x.f;
}
__device__ inline float bflo(unsigned int u) {
  union { unsigned int i; float f; } x; x.i = u << 16; return x.f;
}
__device__ inline float bfhi(unsigned int u) {
  union { unsigned int i; float f; } x; x.i = u & 0xffff0000u; return x.f;
}

// ---- fused: transpose (B,C,N) f32 -> (B*N,C) bf16  |  top-S sample  |  statsR zero ----
__global__ __launch_bounds__(256) void k_prep(
    const float* __restrict__ x, __bf16* __restrict__ xt,
    const float* __restrict__ scores, const int* __restrict__ idxmat,
    int* __restrict__ sampled, float* __restrict__ statsR) {
  const int bid = blockIdx.x;
  const int t   = threadIdx.x;
  if (bid < 4096) {
    __shared__ float tile[32][33];   // [c_local][n_local]
    const int nt = bid & 511, ct = (bid >> 9) & 1, b = bid >> 10;
    const int n0 = nt * 32, c0 = ct * 32;
    const int tx = t & 31, ty = t >> 5;
#pragma unroll
    for (int k = 0; k < 32; k += 8)
      tile[ty + k][tx] = x[((size_t)(b * C_ + c0 + ty + k)) * N_ + n0 + tx];
    __syncthreads();
    const int nl = t >> 3;           // 0..31 (n)
    const int cb = (t & 7) * 4;      // 0..28 (c)
    bf16x4 p;
#pragma unroll
    for (int i = 0; i < 4; ++i) p[i] = (__bf16)tile[cb + i][nl];
    *(bf16x4*)&xt[((size_t)(b * N_ + n0 + nl)) * C_ + c0 + cb] = p;
  } else {
    if (bid == 4096) {
#pragma unroll
      for (int i = 0; i < RST_; ++i) statsR[i * 256 + t] = 0.f;
    }
    const int j = (bid - 4096) * 256 + t;
    const float* sc = scores + (size_t)j * K_;
    const int*   id = idxmat + (size_t)j * K_;
    float sv[K_]; int iv[K_];
#pragma unroll
    for (int k = 0; k < K_; ++k) { sv[k] = sc[k]; iv[k] = id[k]; }
    int* outp = sampled + (size_t)j * S_;
#pragma unroll
    for (int k = 0; k < K_; ++k) {
      const float sk = sv[k];
      int rank = 0;
#pragma unroll
      for (int m = 0; m < K_; ++m)
        rank += ((sv[m] > sk) || (sv[m] == sk && m < k)) ? 1 : 0;
      if (rank < S_) outp[rank] = iv[k];
    }
  }
}

// ---------------- BN stats: per-channel sums (bf16 xt), replicated atomics ----------------
// statsR[r][0:64)=sum_d [64:128)=sumsq_d [128:192)=sum_cen [192:256)=sumsq_cen
__global__ __launch_bounds__(256) void k_stats(const unsigned int* __restrict__ xtu,
                                               const int* __restrict__ sampled,
                                               float* __restrict__ statsR) {
  const int t   = threadIdx.x;
  const int cp  = t & 31;                         // channel pair 0..31
  const int hw0 = (blockIdx.x * 256 + t) >> 5;    // global half-wave id
  const int nh  = gridDim.x * 8;                  // total half-waves
  float sd0 = 0, sd1 = 0, qd0 = 0, qd1 = 0, sc0 = 0, sc1 = 0, qc0 = 0, qc1 = 0;
  // ROWS_ % (2*nh) == 0 for gridDim.x = 1024
  for (int j = hw0; j < ROWS_; j += 2 * nh) {
    const int j2 = j + nh;
    const unsigned int cuA = xtu[(size_t)j  * 32 + cp];
    const unsigned int cuB = xtu[(size_t)j2 * 32 + cp];
    const int siA = (cp < S_) ? sampled[j  * S_ + cp] : 0;
    const int siB = (cp < S_) ? sampled[j2 * S_ + cp] : 0;
    const float a0 = bflo(cuA), a1 = bfhi(cuA);
    const float b0 = bflo(cuB), b1 = bfhi(cuB);
    sc0 += a0 + b0; sc1 += a1 + b1;
    qc0 += a0 * a0 + b0 * b0; qc1 += a1 * a1 + b1 * b1;
#pragma unroll
    for (int s = 0; s < S_; ++s) {
      const int nbA = __shfl(siA, s, 32);
      const int nbB = __shfl(siB, s, 32);
      const unsigned int vA = xtu[(size_t)nbA * 32 + cp];
      const unsigned int vB = xtu[(size_t)nbB * 32 + cp];
      const float dA0 = bflo(vA) - a0, dA1 = bfhi(vA) - a1;
      const float dB0 = bflo(vB) - b0, dB1 = bfhi(vB) - b1;
      sd0 += dA0 + dB0; qd0 += dA0 * dA0 + dB0 * dB0;
      sd1 += dA1 + dB1; qd1 += dA1 * dA1 + dB1 * dB1;
    }
  }
  __shared__ float sred[256];
  sred[t] = 0.f;
  __syncthreads();
  const int c0i = 2 * cp;
  atomicAdd(&sred[c0i], sd0);        atomicAdd(&sred[c0i + 1], sd1);
  atomicAdd(&sred[64 + c0i], qd0);   atomicAdd(&sred[64 + c0i + 1], qd1);
  atomicAdd(&sred[128 + c0i], sc0);  atomicAdd(&sred[128 + c0i + 1], sc1);
  atomicAdd(&sred[192 + c0i], qc0);  atomicAdd(&sred[192 + c0i + 1], qc1);
  __syncthreads();
  atomicAdd(&statsR[(blockIdx.x & (RST_ - 1)) * 256 + t], sred[t]);
}

// ---------------- main: replica-sum + BN-fold + act + split pointwise MFMA + max over S ----------------
__global__ __launch_bounds__(256) void k_main(
    const __bf16* __restrict__ xt, const int* __restrict__ sampled,
    const float* __restrict__ statsR, const float* __restrict__ dww,
    const float* __restrict__ gamma, const float* __restrict__ beta,
    const float* __restrict__ pw, float* __restrict__ out) {
  __shared__ __bf16 dact[160 * 64];   // rows (s*16+r), 128B each, XOR-swizzled
  __shared__ __bf16 cact[16 * 64];    // central act rows
  __shared__ float  ost[16][68];      // output staging; front 256 floats alias ABs

  float* ABs   = &ost[0][0];          // [0:128)=A, [128:256)=B
  float* sstat = (float*)dact;        // transient: summed stats (consumed pre-sync2)

  const int t    = threadIdx.x;
  const int lane = t & 63;
  const int w    = t >> 6;            // wave -> output cols [16w,16w+16)
  const int j0   = blockIdx.x * 16;
  const int b    = j0 / N_;
  const int n0   = j0 % N_;
  const int r    = t >> 4;            // row 0..15
  const int q    = t & 15;            // channel quad

  { // sum stats replicas
    float sv = 0.f;
#pragma unroll
    for (int rr = 0; rr < RST_; ++rr) sv += statsR[rr * 256 + t];
    sstat[t] = sv;
  }
  __syncthreads();

  // fold BN into per-channel affine
  if (t < CH_) {
    float mean_e, var_e;
    if (t < C_) {
      const float cnt = (float)ROWS_ * (float)S_;
      const float su = sstat[t], sq = sstat[64 + t];
      mean_e = su / cnt; var_e = sq / cnt - mean_e * mean_e;
    } else {
      const float cnt = (float)ROWS_;
      const float su = sstat[128 + (t - C_)], sq = sstat[192 + (t - C_)];
      mean_e = su / cnt; var_e = sq / cnt - mean_e * mean_e;
    }
    const float wg = dww[t], g = gamma[t];
    const float inv = rsqrtf(wg * wg * var_e + 1e-5f);
    ABs[t]       = wg * g * inv;
    ABs[CH_ + t] = beta[t] - wg * mean_e * inv * g;
  }
  __syncthreads();   // sstat fully consumed; dact writes may begin after this

  const f32x4 a_d = *(const f32x4*)&ABs[4 * q];
  const f32x4 a_c = *(const f32x4*)&ABs[C_ + 4 * q];
  const f32x4 b_d = *(const f32x4*)&ABs[CH_ + 4 * q];
  const f32x4 b_c = *(const f32x4*)&ABs[CH_ + C_ + 4 * q];

  // central load + c-act (channels 64..127 of edge)
  float cen[4];
  {
    u16x4 cu = *(const u16x4*)&xt[(size_t)(j0 + r) * C_ + 4 * q];
    bf16x4 p;
#pragma unroll
    for (int i = 0; i < 4; ++i) {
      cen[i] = bf2f(cu[i]);
      const float tt = a_c[i] * cen[i] + b_c[i];
      p[i] = (__bf16)fmaxf(tt, 0.2f * tt);
    }
    const int byt = r * 128 + ((8 * q) ^ ((r & 7) << 4));
    *(bf16x4*)((char*)cact + byt) = p;
  }

  // all S neighbor gathers + d-act (channels 0..63 of edge)
  const int* sp = sampled + (size_t)(j0 + r) * S_;
#pragma unroll
  for (int s = 0; s < S_; ++s) {
    const int nb = sp[s];
    u16x4 vu = *(const u16x4*)&xt[(size_t)nb * C_ + 4 * q];
    bf16x4 p;
#pragma unroll
    for (int i = 0; i < 4; ++i) {
      const float d  = bf2f(vu[i]) - cen[i];
      const float tt = a_d[i] * d + b_d[i];
      p[i] = (__bf16)fmaxf(tt, 0.2f * tt);
    }
    const int row = s * 16 + r;
    const int byt = row * 128 + ((8 * q) ^ ((r & 7) << 4));  // (row&7)==(r&7)
    *(bf16x4*)((char*)dact + byt) = p;
  }

  // B-fragments: pw^T; d-part K=[0,64), c-part K=[64,128)
  bf16x8 bfd[2], bfc[2];
  {
    const int o  = 16 * w + (lane & 15);
    const int kb = 8 * (lane >> 4);
#pragma unroll
    for (int ts = 0; ts < 2; ++ts) {
      const int k = 32 * ts + kb;
      f32x4 v0 = *(const f32x4*)&pw[(size_t)o * CH_ + k];
      f32x4 v1 = *(const f32x4*)&pw[(size_t)o * CH_ + k + 4];
      f32x4 w0 = *(const f32x4*)&pw[(size_t)o * CH_ + C_ + k];
      f32x4 w1 = *(const f32x4*)&pw[(size_t)o * CH_ + C_ + k + 4];
      bf16x8 f, g;
#pragma unroll
      for (int i = 0; i < 4; ++i) {
        f[i] = (__bf16)v0[i]; f[4 + i] = (__bf16)v1[i];
        g[i] = (__bf16)w0[i]; g[4 + i] = (__bf16)w1[i];
      }
      bfd[ts] = f; bfc[ts] = g;
    }
  }

  __syncthreads();

  const int arow  = lane & 15;
  const int akoff = 16 * (lane >> 4);
  const int swz   = (arow & 7) << 4;

  f32x4 cacc = {0.f, 0.f, 0.f, 0.f};
#pragma unroll
  for (int ts = 0; ts < 2; ++ts) {
    bf16x8 a = *(bf16x8*)((char*)cact + arow * 128 + ((64 * ts + akoff) ^ swz));
    cacc = __builtin_amdgcn_mfma_f32_16x16x32_bf16(a, bfc[ts], cacc, 0, 0, 0);
  }

  f32x4 rmax;
  rmax[0] = rmax[1] = rmax[2] = rmax[3] = -__builtin_inff();
#pragma unroll
  for (int s = 0; s < S_; ++s) {
    f32x4 acc = {0.f, 0.f, 0.f, 0.f};
#pragma unroll
    for (int ts = 0; ts < 2; ++ts) {
      bf16x8 a = *(bf16x8*)((char*)dact + (s * 16 + arow) * 128 + ((64 * ts + akoff) ^ swz));
      acc = __builtin_amdgcn_mfma_f32_16x16x32_bf16(a, bfd[ts], acc, 0, 0, 0);
    }
#pragma unroll
    for (int i = 0; i < 4; ++i) rmax[i] = fmaxf(rmax[i], acc[i]);
  }

  __syncthreads();   // ABs (aliased on ost) fully consumed before staging writes
  { // stage: C/D mapping col=lane&15, row=4*(lane>>4)+i
    const int ol = lane & 15;
    const int rb = 4 * (lane >> 4);
#pragma unroll
    for (int i = 0; i < 4; ++i) ost[rb + i][16 * w + ol] = rmax[i] + cacc[i];
  }
  __syncthreads();
  { // coalesced store: out[b][o][n0..n0+15]
    const int o  = t >> 2;
    const int sg = t & 3;
    f32x4 v;
#pragma unroll
    for (int i = 0; i < 4; ++i) v[i] = ost[sg * 4 + i][o];
    *(f32x4*)&out[((size_t)(b * OUT_ + o)) * N_ + n0 + sg * 4] = v;
  }
}

extern "C" void kernel_launch(void* const* d_in, const int* in_sizes, int n_in,
                              void* d_out, int out_size, void* d_ws, size_t ws_size,
                              hipStream_t stream) {
  const float* x      = (const float*)d_in[0];
  const int*   cif    = (const int*)  d_in[1];
  const float* scores = (const float*)d_in[2];
  const float* dww    = (const float*)d_in[3];
  const float* pw     = (const float*)d_in[4];
  const float* gamma  = (const float*)d_in[5];
  const float* beta   = (const float*)d_in[6];
  float* out = (float*)d_out;

  char* ws = (char*)d_ws;
  __bf16* xt      = (__bf16*)(ws);                            //  8,388,608 B
  int*    sampled = (int*)   (ws + 8388608);                  //  2,621,440 B
  float*  statsR  = (float*) (ws + 8388608 + 2621440);        //     16,384 B

  k_prep<<<4096 + 256, 256, 0, stream>>>(x, xt, scores, cif, sampled, statsR);
  k_stats<<<1024, 256, 0, stream>>>((const unsigned int*)xt, sampled, statsR);
  k_main<<<ROWS_ / 16, 256, 0, stream>>>(xt, sampled, statsR, dww, gamma, beta, pw, out);
}

// Round 5
// 65.746 us; speedup vs baseline: 1.7262x; 1.1373x over previous
//
#include <hip/hip_runtime.h>
#include <hip/hip_bf16.h>

#define B_   4
#define C_   64
#define N_   16384
#define K_   20
#define S_   10
#define OUT_ 64
#define CH_  128
#define ROWS_ (B_ * N_)
#define RST_ 16   // stats replicas

typedef __attribute__((ext_vector_type(4))) float  f32x4;
typedef __attribute__((ext_vector_type(8))) __bf16 bf16x8;
typedef __attribute__((ext_vector_type(4))) __bf16 bf16x4;
typedef __attribute__((ext_vector_type(4))) unsigned short u16x4;

__device__ inline float bf2f(unsigned short u) {
  union { unsigned int i; float f; } x; x.i = ((unsigned int)u) << 16; return x.f;
}

// ---- fused: transpose (B,C,N) f32 -> (B*N,C) bf16  |  top-S sample  |  statsR zero ----
__global__ __launch_bounds__(256) void k_prep(
    const float* __restrict__ x, __bf16* __restrict__ xt,
    const float* __restrict__ scores, const int* __restrict__ idxmat,
    int* __restrict__ sampled, float* __restrict__ statsR) {
  const int bid = blockIdx.x;
  const int t   = threadIdx.x;
  if (bid < 4096) {
    __shared__ float tile[32][33];   // [c_local][n_local]
    const int nt = bid & 511, ct = (bid >> 9) & 1, b = bid >> 10;
    const int n0 = nt * 32, c0 = ct * 32;
    const int tx = t & 31, ty = t >> 5;
#pragma unroll
    for (int k = 0; k < 32; k += 8)
      tile[ty + k][tx] = x[((size_t)(b * C_ + c0 + ty + k)) * N_ + n0 + tx];
    __syncthreads();
    const int nl = t >> 3;           // 0..31 (n)
    const int cb = (t & 7) * 4;      // 0..28 (c)
    bf16x4 p;
#pragma unroll
    for (int i = 0; i < 4; ++i) p[i] = (__bf16)tile[cb + i][nl];
    *(bf16x4*)&xt[((size_t)(b * N_ + n0 + nl)) * C_ + c0 + cb] = p;
  } else {
    if (bid == 4096) {
#pragma unroll
      for (int i = 0; i < RST_; ++i) statsR[i * 256 + t] = 0.f;
    }
    const int j = (bid - 4096) * 256 + t;
    const float* sc = scores + (size_t)j * K_;
    const int*   id = idxmat + (size_t)j * K_;
    float sv[K_]; int iv[K_];
#pragma unroll
    for (int k = 0; k < K_; ++k) { sv[k] = sc[k]; iv[k] = id[k]; }
    int* outp = sampled + (size_t)j * S_;
#pragma unroll
    for (int k = 0; k < K_; ++k) {
      const float sk = sv[k];
      int rank = 0;
#pragma unroll
      for (int m = 0; m < K_; ++m)
        rank += ((sv[m] > sk) || (sv[m] == sk && m < k)) ? 1 : 0;
      if (rank < S_) outp[rank] = iv[k];
    }
  }
}

// ---------------- BN stats: k_main-style gather, register accum, wave reduce ----------------
// statsR[rep][0:64)=sum_d [64:128)=sumsq_d [128:192)=sum_cen [192:256)=sumsq_cen
__global__ __launch_bounds__(256) void k_stats(const __bf16* __restrict__ xt,
                                               const int* __restrict__ sampled,
                                               float* __restrict__ statsR) {
  const int t    = threadIdx.x;
  const int lane = t & 63;
  const int w    = t >> 6;
  const int r    = t >> 4;            // 0..15
  const int q    = t & 15;            // channel quad
  const int j0   = blockIdx.x * 32;
  const int jA   = j0 + r;
  const int jB   = j0 + 16 + r;

  // preload all indices (coalesced/broadcast within 16-thread groups)
  int ia[S_], ib[S_];
  const int* spA = sampled + (size_t)jA * S_;
  const int* spB = sampled + (size_t)jB * S_;
#pragma unroll
  for (int s = 0; s < S_; ++s) { ia[s] = spA[s]; ib[s] = spB[s]; }

  // central rows
  u16x4 cA = *(const u16x4*)&xt[(size_t)jA * C_ + 4 * q];
  u16x4 cB = *(const u16x4*)&xt[(size_t)jB * C_ + 4 * q];

  // gather all neighbor rows into registers (static unroll -> all in flight)
  u16x4 vA[S_], vB[S_];
#pragma unroll
  for (int s = 0; s < S_; ++s) {
    vA[s] = *(const u16x4*)&xt[(size_t)ia[s] * C_ + 4 * q];
    vB[s] = *(const u16x4*)&xt[(size_t)ib[s] * C_ + 4 * q];
  }

  f32x4 sd = {0,0,0,0}, qd = {0,0,0,0}, sc = {0,0,0,0}, qc = {0,0,0,0};
  float cenA[4], cenB[4];
#pragma unroll
  for (int i = 0; i < 4; ++i) {
    cenA[i] = bf2f(cA[i]); cenB[i] = bf2f(cB[i]);
    sc[i] += cenA[i] + cenB[i];
    qc[i] += cenA[i] * cenA[i] + cenB[i] * cenB[i];
  }
#pragma unroll
  for (int s = 0; s < S_; ++s) {
#pragma unroll
    for (int i = 0; i < 4; ++i) {
      const float dA = bf2f(vA[s][i]) - cenA[i];
      const float dB = bf2f(vB[s][i]) - cenB[i];
      sd[i] += dA + dB;
      qd[i] += dA * dA + dB * dB;
    }
  }

  // reduce across r within wave: lanes differing in bits 4,5 share q
#pragma unroll
  for (int i = 0; i < 4; ++i) {
    sd[i] += __shfl_xor(sd[i], 16); sd[i] += __shfl_xor(sd[i], 32);
    qd[i] += __shfl_xor(qd[i], 16); qd[i] += __shfl_xor(qd[i], 32);
    sc[i] += __shfl_xor(sc[i], 16); sc[i] += __shfl_xor(sc[i], 32);
    qc[i] += __shfl_xor(qc[i], 16); qc[i] += __shfl_xor(qc[i], 32);
  }

  __shared__ float sred[4][4][64];   // [stat][wave][channel]
  if (lane < 16) {
    *(f32x4*)&sred[0][w][4 * q] = sd;
    *(f32x4*)&sred[1][w][4 * q] = qd;
    *(f32x4*)&sred[2][w][4 * q] = sc;
    *(f32x4*)&sred[3][w][4 * q] = qc;
  }
  __syncthreads();
  if (t < 64) {
    float* dst = statsR + (blockIdx.x & (RST_ - 1)) * 256;
#pragma unroll
    for (int k = 0; k < 4; ++k) {
      const float v = sred[k][0][t] + sred[k][1][t] + sred[k][2][t] + sred[k][3][t];
      atomicAdd(&dst[k * 64 + t], v);
    }
  }
}

// ---------------- main: replica-sum + BN-fold + act + split pointwise MFMA + max over S ----------------
__global__ __launch_bounds__(256) void k_main(
    const __bf16* __restrict__ xt, const int* __restrict__ sampled,
    const float* __restrict__ statsR, const float* __restrict__ dww,
    const float* __restrict__ gamma, const float* __restrict__ beta,
    const float* __restrict__ pw, float* __restrict__ out) {
  __shared__ __bf16 dact[160 * 64];   // rows (s*16+r), 128B each, XOR-swizzled
  __shared__ __bf16 cact[16 * 64];    // central act rows
  __shared__ float  ost[16][68];      // output staging; front 256 floats alias ABs

  float* ABs   = &ost[0][0];          // [0:128)=A, [128:256)=B
  float* sstat = (float*)dact;        // transient: summed stats (consumed pre-sync2)

  const int t    = threadIdx.x;
  const int lane = t & 63;
  const int w    = t >> 6;            // wave -> output cols [16w,16w+16)
  const int j0   = blockIdx.x * 16;
  const int b    = j0 / N_;
  const int n0   = j0 % N_;
  const int r    = t >> 4;            // row 0..15
  const int q    = t & 15;            // channel quad

  // preload indices + all gathers into registers (keep loads in flight)
  int nb[S_];
  const int* sp = sampled + (size_t)(j0 + r) * S_;
#pragma unroll
  for (int s = 0; s < S_; ++s) nb[s] = sp[s];
  u16x4 cu = *(const u16x4*)&xt[(size_t)(j0 + r) * C_ + 4 * q];
  u16x4 vu[S_];
#pragma unroll
  for (int s = 0; s < S_; ++s)
    vu[s] = *(const u16x4*)&xt[(size_t)nb[s] * C_ + 4 * q];

  { // sum stats replicas
    float sv = 0.f;
#pragma unroll
    for (int rr = 0; rr < RST_; ++rr) sv += statsR[rr * 256 + t];
    sstat[t] = sv;
  }
  __syncthreads();

  // fold BN into per-channel affine
  if (t < CH_) {
    float mean_e, var_e;
    if (t < C_) {
      const float cnt = (float)ROWS_ * (float)S_;
      const float su = sstat[t], sq = sstat[64 + t];
      mean_e = su / cnt; var_e = sq / cnt - mean_e * mean_e;
    } else {
      const float cnt = (float)ROWS_;
      const float su = sstat[128 + (t - C_)], sq = sstat[192 + (t - C_)];
      mean_e = su / cnt; var_e = sq / cnt - mean_e * mean_e;
    }
    const float wg = dww[t], g = gamma[t];
    const float inv = rsqrtf(wg * wg * var_e + 1e-5f);
    ABs[t]       = wg * g * inv;
    ABs[CH_ + t] = beta[t] - wg * mean_e * inv * g;
  }
  __syncthreads();   // sstat consumed; dact writes may begin

  const f32x4 a_d = *(const f32x4*)&ABs[4 * q];
  const f32x4 a_c = *(const f32x4*)&ABs[C_ + 4 * q];
  const f32x4 b_d = *(const f32x4*)&ABs[CH_ + 4 * q];
  const f32x4 b_c = *(const f32x4*)&ABs[CH_ + C_ + 4 * q];

  // central act (channels 64..127 of edge)
  float cen[4];
  {
    bf16x4 p;
#pragma unroll
    for (int i = 0; i < 4; ++i) {
      cen[i] = bf2f(cu[i]);
      const float tt = a_c[i] * cen[i] + b_c[i];
      p[i] = (__bf16)fmaxf(tt, 0.2f * tt);
    }
    const int byt = r * 128 + ((8 * q) ^ ((r & 7) << 4));
    *(bf16x4*)((char*)cact + byt) = p;
  }

  // d-act (channels 0..63 of edge) from pre-gathered registers
#pragma unroll
  for (int s = 0; s < S_; ++s) {
    bf16x4 p;
#pragma unroll
    for (int i = 0; i < 4; ++i) {
      const float d  = bf2f(vu[s][i]) - cen[i];
      const float tt = a_d[i] * d + b_d[i];
      p[i] = (__bf16)fmaxf(tt, 0.2f * tt);
    }
    const int row = s * 16 + r;
    const int byt = row * 128 + ((8 * q) ^ ((r & 7) << 4));  // (row&7)==(r&7)
    *(bf16x4*)((char*)dact + byt) = p;
  }

  // B-fragments: pw^T; d-part K=[0,64), c-part K=[64,128)
  bf16x8 bfd[2], bfc[2];
  {
    const int o  = 16 * w + (lane & 15);
    const int kb = 8 * (lane >> 4);
#pragma unroll
    for (int ts = 0; ts < 2; ++ts) {
      const int k = 32 * ts + kb;
      f32x4 v0 = *(const f32x4*)&pw[(size_t)o * CH_ + k];
      f32x4 v1 = *(const f32x4*)&pw[(size_t)o * CH_ + k + 4];
      f32x4 w0 = *(const f32x4*)&pw[(size_t)o * CH_ + C_ + k];
      f32x4 w1 = *(const f32x4*)&pw[(size_t)o * CH_ + C_ + k + 4];
      bf16x8 f, g;
#pragma unroll
      for (int i = 0; i < 4; ++i) {
        f[i] = (__bf16)v0[i]; f[4 + i] = (__bf16)v1[i];
        g[i] = (__bf16)w0[i]; g[4 + i] = (__bf16)w1[i];
      }
      bfd[ts] = f; bfc[ts] = g;
    }
  }

  __syncthreads();

  const int arow  = lane & 15;
  const int akoff = 16 * (lane >> 4);
  const int swz   = (arow & 7) << 4;

  f32x4 cacc = {0.f, 0.f, 0.f, 0.f};
#pragma unroll
  for (int ts = 0; ts < 2; ++ts) {
    bf16x8 a = *(bf16x8*)((char*)cact + arow * 128 + ((64 * ts + akoff) ^ swz));
    cacc = __builtin_amdgcn_mfma_f32_16x16x32_bf16(a, bfc[ts], cacc, 0, 0, 0);
  }

  f32x4 rmax;
  rmax[0] = rmax[1] = rmax[2] = rmax[3] = -__builtin_inff();
#pragma unroll
  for (int s = 0; s < S_; ++s) {
    f32x4 acc = {0.f, 0.f, 0.f, 0.f};
#pragma unroll
    for (int ts = 0; ts < 2; ++ts) {
      bf16x8 a = *(bf16x8*)((char*)dact + (s * 16 + arow) * 128 + ((64 * ts + akoff) ^ swz));
      acc = __builtin_amdgcn_mfma_f32_16x16x32_bf16(a, bfd[ts], acc, 0, 0, 0);
    }
#pragma unroll
    for (int i = 0; i < 4; ++i) rmax[i] = fmaxf(rmax[i], acc[i]);
  }

  __syncthreads();   // ABs (aliased on ost) fully consumed before staging writes
  { // stage: C/D mapping col=lane&15, row=4*(lane>>4)+i
    const int ol = lane & 15;
    const int rb = 4 * (lane >> 4);
#pragma unroll
    for (int i = 0; i < 4; ++i) ost[rb + i][16 * w + ol] = rmax[i] + cacc[i];
  }
  __syncthreads();
  { // coalesced store: out[b][o][n0..n0+15]
    const int o  = t >> 2;
    const int sg = t & 3;
    f32x4 v;
#pragma unroll
    for (int i = 0; i < 4; ++i) v[i] = ost[sg * 4 + i][o];
    *(f32x4*)&out[((size_t)(b * OUT_ + o)) * N_ + n0 + sg * 4] = v;
  }
}

extern "C" void kernel_launch(void* const* d_in, const int* in_sizes, int n_in,
                              void* d_out, int out_size, void* d_ws, size_t ws_size,
                              hipStream_t stream) {
  const float* x      = (const float*)d_in[0];
  const int*   cif    = (const int*)  d_in[1];
  const float* scores = (const float*)d_in[2];
  const float* dww    = (const float*)d_in[3];
  const float* pw     = (const float*)d_in[4];
  const float* gamma  = (const float*)d_in[5];
  const float* beta   = (const float*)d_in[6];
  float* out = (float*)d_out;

  char* ws = (char*)d_ws;
  __bf16* xt      = (__bf16*)(ws);                            //  8,388,608 B
  int*    sampled = (int*)   (ws + 8388608);                  //  2,621,440 B
  float*  statsR  = (float*) (ws + 8388608 + 2621440);        //     16,384 B

  k_prep<<<4096 + 256, 256, 0, stream>>>(x, xt, scores, cif, sampled, statsR);
  k_stats<<<ROWS_ / 32, 256, 0, stream>>>(xt, sampled, statsR);
  k_main<<<ROWS_ / 16, 256, 0, stream>>>(xt, sampled, statsR, dww, gamma, beta, pw, out);
}

// Round 6
// 65.366 us; speedup vs baseline: 1.7362x; 1.0058x over previous
//
#include <hip/hip_runtime.h>
#include <hip/hip_bf16.h>

#define B_   4
#define C_   64
#define N_   16384
#define K_   20
#define S_   10
#define OUT_ 64
#define CH_  128
#define ROWS_ (B_ * N_)
#define RST_ 16   // stats replicas

typedef __attribute__((ext_vector_type(4))) float  f32x4;
typedef __attribute__((ext_vector_type(8))) __bf16 bf16x8;
typedef __attribute__((ext_vector_type(4))) __bf16 bf16x4;
typedef __attribute__((ext_vector_type(4))) unsigned short u16x4;

__device__ inline float bf2f(unsigned short u) {
  union { unsigned int i; float f; } x; x.i = ((unsigned int)u) << 16; return x.f;
}

// ---- fused: transpose (B,C,N) f32 -> (B*N,C) bf16  |  top-S sample  |  statsR zero ----
__global__ __launch_bounds__(256) void k_prep(
    const float* __restrict__ x, __bf16* __restrict__ xt,
    const float* __restrict__ scores, const int* __restrict__ idxmat,
    int* __restrict__ sampled, float* __restrict__ statsR) {
  const int bid = blockIdx.x;
  const int t   = threadIdx.x;
  if (bid < 4096) {
    __shared__ float tile[32][33];   // [c_local][n_local]
    const int nt = bid & 511, ct = (bid >> 9) & 1, b = bid >> 10;
    const int n0 = nt * 32, c0 = ct * 32;
    const int tx = t & 31, ty = t >> 5;
#pragma unroll
    for (int k = 0; k < 32; k += 8)
      tile[ty + k][tx] = x[((size_t)(b * C_ + c0 + ty + k)) * N_ + n0 + tx];
    __syncthreads();
    const int nl = t >> 3;           // 0..31 (n)
    const int cb = (t & 7) * 4;      // 0..28 (c)
    bf16x4 p;
#pragma unroll
    for (int i = 0; i < 4; ++i) p[i] = (__bf16)tile[cb + i][nl];
    *(bf16x4*)&xt[((size_t)(b * N_ + n0 + nl)) * C_ + c0 + cb] = p;
  } else {
    if (bid == 4096) {
#pragma unroll
      for (int i = 0; i < RST_; ++i) statsR[i * 256 + t] = 0.f;
    }
    const int j = (bid - 4096) * 256 + t;
    const float* sc = scores + (size_t)j * K_;
    const int*   id = idxmat + (size_t)j * K_;
    float sv[K_]; int iv[K_];
#pragma unroll
    for (int k = 0; k < K_; ++k) { sv[k] = sc[k]; iv[k] = id[k]; }
    int* outp = sampled + (size_t)j * S_;
#pragma unroll
    for (int k = 0; k < K_; ++k) {
      const float sk = sv[k];
      int rank = 0;
#pragma unroll
      for (int m = 0; m < K_; ++m)
        rank += ((sv[m] > sk) || (sv[m] == sk && m < k)) ? 1 : 0;
      if (rank < S_) outp[rank] = iv[k];
    }
  }
}

// ---------------- BN stats: gather, register accum, wave reduce, replicated atomics ----------------
// statsR[rep][0:64)=sum_d [64:128)=sumsq_d [128:192)=sum_cen [192:256)=sumsq_cen
__global__ __launch_bounds__(256) void k_stats(const __bf16* __restrict__ xt,
                                               const int* __restrict__ sampled,
                                               float* __restrict__ statsR) {
  const int t    = threadIdx.x;
  const int lane = t & 63;
  const int w    = t >> 6;
  const int r    = t >> 4;            // 0..15
  const int q    = t & 15;            // channel quad
  const int j0   = blockIdx.x * 32;
  const int jA   = j0 + r;
  const int jB   = j0 + 16 + r;

  int ia[S_], ib[S_];
  const int* spA = sampled + (size_t)jA * S_;
  const int* spB = sampled + (size_t)jB * S_;
#pragma unroll
  for (int s = 0; s < S_; ++s) { ia[s] = spA[s]; ib[s] = spB[s]; }

  u16x4 cA = *(const u16x4*)&xt[(size_t)jA * C_ + 4 * q];
  u16x4 cB = *(const u16x4*)&xt[(size_t)jB * C_ + 4 * q];

  u16x4 vA[S_], vB[S_];
#pragma unroll
  for (int s = 0; s < S_; ++s) {
    vA[s] = *(const u16x4*)&xt[(size_t)ia[s] * C_ + 4 * q];
    vB[s] = *(const u16x4*)&xt[(size_t)ib[s] * C_ + 4 * q];
  }

  f32x4 sd = {0,0,0,0}, qd = {0,0,0,0}, sc = {0,0,0,0}, qc = {0,0,0,0};
  float cenA[4], cenB[4];
#pragma unroll
  for (int i = 0; i < 4; ++i) {
    cenA[i] = bf2f(cA[i]); cenB[i] = bf2f(cB[i]);
    sc[i] += cenA[i] + cenB[i];
    qc[i] += cenA[i] * cenA[i] + cenB[i] * cenB[i];
  }
#pragma unroll
  for (int s = 0; s < S_; ++s) {
#pragma unroll
    for (int i = 0; i < 4; ++i) {
      const float dA = bf2f(vA[s][i]) - cenA[i];
      const float dB = bf2f(vB[s][i]) - cenB[i];
      sd[i] += dA + dB;
      qd[i] += dA * dA + dB * dB;
    }
  }

#pragma unroll
  for (int i = 0; i < 4; ++i) {
    sd[i] += __shfl_xor(sd[i], 16); sd[i] += __shfl_xor(sd[i], 32);
    qd[i] += __shfl_xor(qd[i], 16); qd[i] += __shfl_xor(qd[i], 32);
    sc[i] += __shfl_xor(sc[i], 16); sc[i] += __shfl_xor(sc[i], 32);
    qc[i] += __shfl_xor(qc[i], 16); qc[i] += __shfl_xor(qc[i], 32);
  }

  __shared__ float sred[4][4][64];   // [stat][wave][channel]
  if (lane < 16) {
    *(f32x4*)&sred[0][w][4 * q] = sd;
    *(f32x4*)&sred[1][w][4 * q] = qd;
    *(f32x4*)&sred[2][w][4 * q] = sc;
    *(f32x4*)&sred[3][w][4 * q] = qc;
  }
  __syncthreads();
  if (t < 64) {
    float* dst = statsR + (blockIdx.x & (RST_ - 1)) * 256;
#pragma unroll
    for (int k = 0; k < 4; ++k) {
      const float v = sred[k][0][t] + sred[k][1][t] + sred[k][2][t] + sred[k][3][t];
      atomicAdd(&dst[k * 64 + t], v);
    }
  }
}

// ---------------- fold: replica-sum + BN fold -> AB[256] ----------------
__global__ void k_fold(const float* __restrict__ statsR, const float* __restrict__ dww,
                       const float* __restrict__ gamma, const float* __restrict__ beta,
                       float* __restrict__ AB) {
  __shared__ float sstat[256];
  const int t = threadIdx.x;   // 256 threads
  float sv = 0.f;
#pragma unroll
  for (int rr = 0; rr < RST_; ++rr) sv += statsR[rr * 256 + t];
  sstat[t] = sv;
  __syncthreads();
  if (t < CH_) {
    float mean_e, var_e;
    if (t < C_) {
      const float cnt = (float)ROWS_ * (float)S_;
      const float su = sstat[t], sq = sstat[64 + t];
      mean_e = su / cnt; var_e = sq / cnt - mean_e * mean_e;
    } else {
      const float cnt = (float)ROWS_;
      const float su = sstat[128 + (t - C_)], sq = sstat[192 + (t - C_)];
      mean_e = su / cnt; var_e = sq / cnt - mean_e * mean_e;
    }
    const float wg = dww[t], g = gamma[t];
    const float inv = rsqrtf(wg * wg * var_e + 1e-5f);
    AB[t]       = wg * g * inv;
    AB[CH_ + t] = beta[t] - wg * mean_e * inv * g;
  }
}

// ---------------- main: act + split pointwise MFMA + max over S ----------------
__global__ __launch_bounds__(256) void k_main(
    const __bf16* __restrict__ xt, const int* __restrict__ sampled,
    const float* __restrict__ AB, const float* __restrict__ pw,
    float* __restrict__ out) {
  __shared__ __bf16 dact[160 * 64];   // 20480 B; rows (s*16+r), 128B each, XOR-swizzled
  __shared__ __bf16 cact[16 * 64];    //  2048 B; central act rows
  float* ost = (float*)dact;          // epilogue alias: [16][68] = 4352 B (dact dead by then)

  const int t    = threadIdx.x;
  const int lane = t & 63;
  const int w    = t >> 6;            // wave -> output cols [16w,16w+16)
  const int j0   = blockIdx.x * 16;
  const int b    = j0 / N_;
  const int n0   = j0 % N_;
  const int r    = t >> 4;            // row 0..15
  const int q    = t & 15;            // channel quad

  // preload indices + all gathers into registers (keep loads in flight)
  int nb[S_];
  const int* sp = sampled + (size_t)(j0 + r) * S_;
#pragma unroll
  for (int s = 0; s < S_; ++s) nb[s] = sp[s];
  u16x4 cu = *(const u16x4*)&xt[(size_t)(j0 + r) * C_ + 4 * q];
  u16x4 vu[S_];
#pragma unroll
  for (int s = 0; s < S_; ++s)
    vu[s] = *(const u16x4*)&xt[(size_t)nb[s] * C_ + 4 * q];

  const f32x4 a_d = *(const f32x4*)&AB[4 * q];
  const f32x4 a_c = *(const f32x4*)&AB[C_ + 4 * q];
  const f32x4 b_d = *(const f32x4*)&AB[CH_ + 4 * q];
  const f32x4 b_c = *(const f32x4*)&AB[CH_ + C_ + 4 * q];

  // central act (channels 64..127 of edge)
  float cen[4];
  {
    bf16x4 p;
#pragma unroll
    for (int i = 0; i < 4; ++i) {
      cen[i] = bf2f(cu[i]);
      const float tt = a_c[i] * cen[i] + b_c[i];
      p[i] = (__bf16)fmaxf(tt, 0.2f * tt);
    }
    const int byt = r * 128 + ((8 * q) ^ ((r & 7) << 4));
    *(bf16x4*)((char*)cact + byt) = p;
  }

  // d-act (channels 0..63 of edge) from pre-gathered registers
#pragma unroll
  for (int s = 0; s < S_; ++s) {
    bf16x4 p;
#pragma unroll
    for (int i = 0; i < 4; ++i) {
      const float d  = bf2f(vu[s][i]) - cen[i];
      const float tt = a_d[i] * d + b_d[i];
      p[i] = (__bf16)fmaxf(tt, 0.2f * tt);
    }
    const int row = s * 16 + r;
    const int byt = row * 128 + ((8 * q) ^ ((r & 7) << 4));  // (row&7)==(r&7)
    *(bf16x4*)((char*)dact + byt) = p;
  }

  // B-fragments: pw^T; d-part K=[0,64), c-part K=[64,128)
  bf16x8 bfd[2], bfc[2];
  {
    const int o  = 16 * w + (lane & 15);
    const int kb = 8 * (lane >> 4);
#pragma unroll
    for (int ts = 0; ts < 2; ++ts) {
      const int k = 32 * ts + kb;
      f32x4 v0 = *(const f32x4*)&pw[(size_t)o * CH_ + k];
      f32x4 v1 = *(const f32x4*)&pw[(size_t)o * CH_ + k + 4];
      f32x4 w0 = *(const f32x4*)&pw[(size_t)o * CH_ + C_ + k];
      f32x4 w1 = *(const f32x4*)&pw[(size_t)o * CH_ + C_ + k + 4];
      bf16x8 f, g;
#pragma unroll
      for (int i = 0; i < 4; ++i) {
        f[i] = (__bf16)v0[i]; f[4 + i] = (__bf16)v1[i];
        g[i] = (__bf16)w0[i]; g[4 + i] = (__bf16)w1[i];
      }
      bfd[ts] = f; bfc[ts] = g;
    }
  }

  __syncthreads();

  const int arow  = lane & 15;
  const int akoff = 16 * (lane >> 4);
  const int swz   = (arow & 7) << 4;

  f32x4 cacc = {0.f, 0.f, 0.f, 0.f};
#pragma unroll
  for (int ts = 0; ts < 2; ++ts) {
    bf16x8 a = *(bf16x8*)((char*)cact + arow * 128 + ((64 * ts + akoff) ^ swz));
    cacc = __builtin_amdgcn_mfma_f32_16x16x32_bf16(a, bfc[ts], cacc, 0, 0, 0);
  }

  f32x4 rmax;
  rmax[0] = rmax[1] = rmax[2] = rmax[3] = -__builtin_inff();
#pragma unroll
  for (int s = 0; s < S_; ++s) {
    f32x4 acc = {0.f, 0.f, 0.f, 0.f};
#pragma unroll
    for (int ts = 0; ts < 2; ++ts) {
      bf16x8 a = *(bf16x8*)((char*)dact + (s * 16 + arow) * 128 + ((64 * ts + akoff) ^ swz));
      acc = __builtin_amdgcn_mfma_f32_16x16x32_bf16(a, bfd[ts], acc, 0, 0, 0);
    }
#pragma unroll
    for (int i = 0; i < 4; ++i) rmax[i] = fmaxf(rmax[i], acc[i]);
  }

  __syncthreads();   // dact fully consumed; safe to reuse as ost
  { // stage: C/D mapping col=lane&15, row=4*(lane>>4)+i
    const int ol = lane & 15;
    const int rb = 4 * (lane >> 4);
#pragma unroll
    for (int i = 0; i < 4; ++i) ost[(rb + i) * 68 + 16 * w + ol] = rmax[i] + cacc[i];
  }
  __syncthreads();
  { // coalesced store: out[b][o][n0..n0+15]
    const int o  = t >> 2;
    const int sg = t & 3;
    f32x4 v;
#pragma unroll
    for (int i = 0; i < 4; ++i) v[i] = ost[(sg * 4 + i) * 68 + o];
    *(f32x4*)&out[((size_t)(b * OUT_ + o)) * N_ + n0 + sg * 4] = v;
  }
}

extern "C" void kernel_launch(void* const* d_in, const int* in_sizes, int n_in,
                              void* d_out, int out_size, void* d_ws, size_t ws_size,
                              hipStream_t stream) {
  const float* x      = (const float*)d_in[0];
  const int*   cif    = (const int*)  d_in[1];
  const float* scores = (const float*)d_in[2];
  const float* dww    = (const float*)d_in[3];
  const float* pw     = (const float*)d_in[4];
  const float* gamma  = (const float*)d_in[5];
  const float* beta   = (const float*)d_in[6];
  float* out = (float*)d_out;

  char* ws = (char*)d_ws;
  __bf16* xt      = (__bf16*)(ws);                            //  8,388,608 B
  int*    sampled = (int*)   (ws + 8388608);                  //  2,621,440 B
  float*  statsR  = (float*) (ws + 8388608 + 2621440);        //     16,384 B
  float*  AB      = (float*) (ws + 8388608 + 2621440 + 16384);//      1,024 B

  k_prep<<<4096 + 256, 256, 0, stream>>>(x, xt, scores, cif, sampled, statsR);
  k_stats<<<ROWS_ / 32, 256, 0, stream>>>(xt, sampled, statsR);
  k_fold<<<1, 256, 0, stream>>>(statsR, dww, gamma, beta, AB);
  k_main<<<ROWS_ / 16, 256, 0, stream>>>(xt, sampled, AB, pw, out);
}

// Round 7
// 57.478 us; speedup vs baseline: 1.9745x; 1.1372x over previous
//
#include <hip/hip_runtime.h>
#include <hip/hip_bf16.h>

#define B_   4
#define C_   64
#define N_   16384
#define K_   20
#define S_   10
#define OUT_ 64
#define CH_  128
#define ROWS_ (B_ * N_)
#define RST_ 16   // stats replicas

typedef __attribute__((ext_vector_type(4))) float  f32x4;
typedef __attribute__((ext_vector_type(8))) __bf16 bf16x8;
typedef __attribute__((ext_vector_type(4))) __bf16 bf16x4;
typedef __attribute__((ext_vector_type(4))) unsigned short u16x4;

__device__ inline float bf2f(unsigned short u) {
  union { unsigned int i; float f; } x; x.i = ((unsigned int)u) << 16; return x.f;
}

// ---- fused: transpose -> bf16 xt | top-S sample | statsR zero | pw bf16 prepack ----
__global__ __launch_bounds__(256) void k_prep(
    const float* __restrict__ x, __bf16* __restrict__ xt,
    const float* __restrict__ scores, const int* __restrict__ idxmat,
    int* __restrict__ sampled, float* __restrict__ statsR,
    const float* __restrict__ pw, __bf16* __restrict__ pwb) {
  const int bid = blockIdx.x;
  const int t   = threadIdx.x;
  if (bid < 4096) {
    __shared__ float tile[32][33];   // [c_local][n_local]
    const int nt = bid & 511, ct = (bid >> 9) & 1, b = bid >> 10;
    const int n0 = nt * 32, c0 = ct * 32;
    const int tx = t & 31, ty = t >> 5;
#pragma unroll
    for (int k = 0; k < 32; k += 8)
      tile[ty + k][tx] = x[((size_t)(b * C_ + c0 + ty + k)) * N_ + n0 + tx];
    __syncthreads();
    const int nl = t >> 3;           // 0..31 (n)
    const int cb = (t & 7) * 4;      // 0..28 (c)
    bf16x4 p;
#pragma unroll
    for (int i = 0; i < 4; ++i) p[i] = (__bf16)tile[cb + i][nl];
    *(bf16x4*)&xt[((size_t)(b * N_ + n0 + nl)) * C_ + c0 + cb] = p;
  } else if (bid < 4352) {
    if (bid == 4096) {
#pragma unroll
      for (int i = 0; i < RST_; ++i) statsR[i * 256 + t] = 0.f;
    }
    const int j = (bid - 4096) * 256 + t;
    const float* sc = scores + (size_t)j * K_;
    const int*   id = idxmat + (size_t)j * K_;
    float sv[K_]; int iv[K_];
#pragma unroll
    for (int k = 0; k < K_; ++k) { sv[k] = sc[k]; iv[k] = id[k]; }
    int* outp = sampled + (size_t)j * S_;
#pragma unroll
    for (int k = 0; k < K_; ++k) {
      const float sk = sv[k];
      int rank = 0;
#pragma unroll
      for (int m = 0; m < K_; ++m)
        rank += ((sv[m] > sk) || (sv[m] == sk && m < k)) ? 1 : 0;
      if (rank < S_) outp[rank] = iv[k];
    }
  } else {
    // pack pw (OUT,2C) f32 -> per-thread bf16 fragments [256][32]
    const int o  = 16 * (t >> 6) + (t & 15);
    const int kb = 8 * ((t >> 4) & 3);
    const float* src = pw + (size_t)o * CH_;
    __bf16* dst = pwb + t * 32;
#pragma unroll
    for (int ts = 0; ts < 2; ++ts)
#pragma unroll
      for (int i = 0; i < 8; ++i) {
        dst[ts * 8 + i]      = (__bf16)src[32 * ts + kb + i];        // d-part
        dst[16 + ts * 8 + i] = (__bf16)src[C_ + 32 * ts + kb + i];   // c-part
      }
  }
}

// ---------------- BN stats: MLP-forced gather, register accum, wave reduce ----------------
// statsR[rep][0:64)=sum_d [64:128)=sumsq_d [128:192)=sum_cen [192:256)=sumsq_cen
__global__ __launch_bounds__(256, 4) void k_stats(const __bf16* __restrict__ xt,
                                                  const int* __restrict__ sampled,
                                                  float* __restrict__ statsR) {
  const int t    = threadIdx.x;
  const int lane = t & 63;
  const int w    = t >> 6;
  const int r    = t >> 4;            // 0..15
  const int q    = t & 15;            // channel quad
  const int j0   = blockIdx.x * 32;
  const int jA   = j0 + r;
  const int jB   = j0 + 16 + r;

  int ia[S_], ib[S_];
  const int* spA = sampled + (size_t)jA * S_;
  const int* spB = sampled + (size_t)jB * S_;
#pragma unroll
  for (int s = 0; s < S_; ++s) { ia[s] = spA[s]; ib[s] = spB[s]; }

  u16x4 cA = *(const u16x4*)&xt[jA * C_ + 4 * q];
  u16x4 cB = *(const u16x4*)&xt[jB * C_ + 4 * q];

  u16x4 vA[S_], vB[S_];
#pragma unroll
  for (int s = 0; s < S_; ++s) {
    vA[s] = *(const u16x4*)&xt[ia[s] * C_ + 4 * q];
    vB[s] = *(const u16x4*)&xt[ib[s] * C_ + 4 * q];
  }
  __builtin_amdgcn_sched_barrier(0);   // all loads issued before any compute

  f32x4 sd = {0,0,0,0}, qd = {0,0,0,0}, sc = {0,0,0,0}, qc = {0,0,0,0};
  float cenA[4], cenB[4];
#pragma unroll
  for (int i = 0; i < 4; ++i) {
    cenA[i] = bf2f(cA[i]); cenB[i] = bf2f(cB[i]);
    sc[i] += cenA[i] + cenB[i];
    qc[i] += cenA[i] * cenA[i] + cenB[i] * cenB[i];
  }
#pragma unroll
  for (int s = 0; s < S_; ++s) {
#pragma unroll
    for (int i = 0; i < 4; ++i) {
      const float dA = bf2f(vA[s][i]) - cenA[i];
      const float dB = bf2f(vB[s][i]) - cenB[i];
      sd[i] += dA + dB;
      qd[i] += dA * dA + dB * dB;
    }
  }

#pragma unroll
  for (int i = 0; i < 4; ++i) {
    sd[i] += __shfl_xor(sd[i], 16); sd[i] += __shfl_xor(sd[i], 32);
    qd[i] += __shfl_xor(qd[i], 16); qd[i] += __shfl_xor(qd[i], 32);
    sc[i] += __shfl_xor(sc[i], 16); sc[i] += __shfl_xor(sc[i], 32);
    qc[i] += __shfl_xor(qc[i], 16); qc[i] += __shfl_xor(qc[i], 32);
  }

  __shared__ float sred[4][4][64];   // [stat][wave][channel]
  if (lane < 16) {
    *(f32x4*)&sred[0][w][4 * q] = sd;
    *(f32x4*)&sred[1][w][4 * q] = qd;
    *(f32x4*)&sred[2][w][4 * q] = sc;
    *(f32x4*)&sred[3][w][4 * q] = qc;
  }
  __syncthreads();
  if (t < 64) {
    float* dst = statsR + (blockIdx.x & (RST_ - 1)) * 256;
#pragma unroll
    for (int k = 0; k < 4; ++k) {
      const float v = sred[k][0][t] + sred[k][1][t] + sred[k][2][t] + sred[k][3][t];
      atomicAdd(&dst[k * 64 + t], v);
    }
  }
}

// ---------------- fold: replica-sum + BN fold -> AB[256] ----------------
__global__ void k_fold(const float* __restrict__ statsR, const float* __restrict__ dww,
                       const float* __restrict__ gamma, const float* __restrict__ beta,
                       float* __restrict__ AB) {
  __shared__ float sstat[256];
  const int t = threadIdx.x;   // 256 threads
  float sv = 0.f;
#pragma unroll
  for (int rr = 0; rr < RST_; ++rr) sv += statsR[rr * 256 + t];
  sstat[t] = sv;
  __syncthreads();
  if (t < CH_) {
    float mean_e, var_e;
    if (t < C_) {
      const float cnt = (float)ROWS_ * (float)S_;
      const float su = sstat[t], sq = sstat[64 + t];
      mean_e = su / cnt; var_e = sq / cnt - mean_e * mean_e;
    } else {
      const float cnt = (float)ROWS_;
      const float su = sstat[128 + (t - C_)], sq = sstat[192 + (t - C_)];
      mean_e = su / cnt; var_e = sq / cnt - mean_e * mean_e;
    }
    const float wg = dww[t], g = gamma[t];
    const float inv = rsqrtf(wg * wg * var_e + 1e-5f);
    AB[t]       = wg * g * inv;
    AB[CH_ + t] = beta[t] - wg * mean_e * inv * g;
  }
}

// ---------------- main: MLP-forced gather + act + split pointwise MFMA + max over S ----------------
__global__ __launch_bounds__(256, 4) void k_main(
    const __bf16* __restrict__ xt, const int* __restrict__ sampled,
    const float* __restrict__ AB, const __bf16* __restrict__ pwb,
    float* __restrict__ out) {
  __shared__ __bf16 dact[160 * 64];   // 20480 B; rows (s*16+r), 128B each, XOR-swizzled
  __shared__ __bf16 cact[16 * 64];    //  2048 B
  float* ost = (float*)dact;          // epilogue alias (dact dead by then)

  const int t    = threadIdx.x;
  const int lane = t & 63;
  const int w    = t >> 6;            // wave -> output cols [16w,16w+16)
  const int j0   = blockIdx.x * 16;
  const int b    = j0 / N_;
  const int n0   = j0 % N_;
  const int r    = t >> 4;            // row 0..15
  const int q    = t & 15;            // channel quad

  // ---- load phase: everything in flight before any compute ----
  int nb[S_];
  const int* sp = sampled + (size_t)(j0 + r) * S_;
#pragma unroll
  for (int s = 0; s < S_; ++s) nb[s] = sp[s];
  u16x4 cu = *(const u16x4*)&xt[(j0 + r) * C_ + 4 * q];
  u16x4 vu[S_];
#pragma unroll
  for (int s = 0; s < S_; ++s)
    vu[s] = *(const u16x4*)&xt[nb[s] * C_ + 4 * q];

  const f32x4 a_d = *(const f32x4*)&AB[4 * q];
  const f32x4 a_c = *(const f32x4*)&AB[C_ + 4 * q];
  const f32x4 b_d = *(const f32x4*)&AB[CH_ + 4 * q];
  const f32x4 b_c = *(const f32x4*)&AB[CH_ + C_ + 4 * q];

  bf16x8 bfd[2], bfc[2];
  {
    const bf16x8* fp = (const bf16x8*)(pwb + t * 32);
    bfd[0] = fp[0]; bfd[1] = fp[1]; bfc[0] = fp[2]; bfc[1] = fp[3];
  }
  __builtin_amdgcn_sched_barrier(0);

  // ---- compute phase ----
  float cen[4];
  {
    bf16x4 p;
#pragma unroll
    for (int i = 0; i < 4; ++i) {
      cen[i] = bf2f(cu[i]);
      const float tt = a_c[i] * cen[i] + b_c[i];
      p[i] = (__bf16)fmaxf(tt, 0.2f * tt);
    }
    const int byt = r * 128 + ((8 * q) ^ ((r & 7) << 4));
    *(bf16x4*)((char*)cact + byt) = p;
  }

#pragma unroll
  for (int s = 0; s < S_; ++s) {
    bf16x4 p;
#pragma unroll
    for (int i = 0; i < 4; ++i) {
      const float d  = bf2f(vu[s][i]) - cen[i];
      const float tt = a_d[i] * d + b_d[i];
      p[i] = (__bf16)fmaxf(tt, 0.2f * tt);
    }
    const int row = s * 16 + r;
    const int byt = row * 128 + ((8 * q) ^ ((r & 7) << 4));  // (row&7)==(r&7)
    *(bf16x4*)((char*)dact + byt) = p;
  }

  __syncthreads();

  const int arow  = lane & 15;
  const int akoff = 16 * (lane >> 4);
  const int swz   = (arow & 7) << 4;

  f32x4 cacc = {0.f, 0.f, 0.f, 0.f};
#pragma unroll
  for (int ts = 0; ts < 2; ++ts) {
    bf16x8 a = *(bf16x8*)((char*)cact + arow * 128 + ((64 * ts + akoff) ^ swz));
    cacc = __builtin_amdgcn_mfma_f32_16x16x32_bf16(a, bfc[ts], cacc, 0, 0, 0);
  }

  f32x4 rmax;
  rmax[0] = rmax[1] = rmax[2] = rmax[3] = -__builtin_inff();
#pragma unroll
  for (int s = 0; s < S_; ++s) {
    f32x4 acc = {0.f, 0.f, 0.f, 0.f};
#pragma unroll
    for (int ts = 0; ts < 2; ++ts) {
      bf16x8 a = *(bf16x8*)((char*)dact + (s * 16 + arow) * 128 + ((64 * ts + akoff) ^ swz));
      acc = __builtin_amdgcn_mfma_f32_16x16x32_bf16(a, bfd[ts], acc, 0, 0, 0);
    }
#pragma unroll
    for (int i = 0; i < 4; ++i) rmax[i] = fmaxf(rmax[i], acc[i]);
  }

  __syncthreads();   // dact fully consumed; reuse as ost
  {
    const int ol = lane & 15;
    const int rb = 4 * (lane >> 4);
#pragma unroll
    for (int i = 0; i < 4; ++i) ost[(rb + i) * 68 + 16 * w + ol] = rmax[i] + cacc[i];
  }
  __syncthreads();
  {
    const int o  = t >> 2;
    const int sg = t & 3;
    f32x4 v;
#pragma unroll
    for (int i = 0; i < 4; ++i) v[i] = ost[(sg * 4 + i) * 68 + o];
    *(f32x4*)&out[((size_t)(b * OUT_ + o)) * N_ + n0 + sg * 4] = v;
  }
}

extern "C" void kernel_launch(void* const* d_in, const int* in_sizes, int n_in,
                              void* d_out, int out_size, void* d_ws, size_t ws_size,
                              hipStream_t stream) {
  const float* x      = (const float*)d_in[0];
  const int*   cif    = (const int*)  d_in[1];
  const float* scores = (const float*)d_in[2];
  const float* dww    = (const float*)d_in[3];
  const float* pw     = (const float*)d_in[4];
  const float* gamma  = (const float*)d_in[5];
  const float* beta   = (const float*)d_in[6];
  float* out = (float*)d_out;

  char* ws = (char*)d_ws;
  __bf16* xt      = (__bf16*)(ws);                                  //  8,388,608 B
  int*    sampled = (int*)   (ws + 8388608);                        //  2,621,440 B
  float*  statsR  = (float*) (ws + 8388608 + 2621440);              //     16,384 B
  float*  AB      = (float*) (ws + 8388608 + 2621440 + 16384);      //      1,024 B
  __bf16* pwb     = (__bf16*)(ws + 8388608 + 2621440 + 16384 + 1024); //   16,384 B

  k_prep<<<4096 + 256 + 1, 256, 0, stream>>>(x, xt, scores, cif, sampled, statsR, pw, pwb);
  k_stats<<<ROWS_ / 32, 256, 0, stream>>>(xt, sampled, statsR);
  k_fold<<<1, 256, 0, stream>>>(statsR, dww, gamma, beta, AB);
  k_main<<<ROWS_ / 16, 256, 0, stream>>>(xt, sampled, AB, pwb, out);
}

// Round 8
// 56.553 us; speedup vs baseline: 2.0068x; 1.0164x over previous
//
#include <hip/hip_runtime.h>
#include <hip/hip_bf16.h>

#define B_   4
#define C_   64
#define N_   16384
#define K_   20
#define S_   10
#define OUT_ 64
#define CH_  128
#define ROWS_ (B_ * N_)
#define RST_ 16   // stats replicas

typedef __attribute__((ext_vector_type(4))) float  f32x4;
typedef __attribute__((ext_vector_type(8))) __bf16 bf16x8;
typedef __attribute__((ext_vector_type(4))) __bf16 bf16x4;
typedef __attribute__((ext_vector_type(4))) unsigned short u16x4;

__device__ inline float bf2f(unsigned short u) {
  union { unsigned int i; float f; } x; x.i = ((unsigned int)u) << 16; return x.f;
}

// ---- fused: transpose -> bf16 xt | top-S sample | statsR zero | pw bf16 prepack ----
__global__ __launch_bounds__(256) void k_prep(
    const float* __restrict__ x, __bf16* __restrict__ xt,
    const float* __restrict__ scores, const int* __restrict__ idxmat,
    int* __restrict__ sampled, float* __restrict__ statsR,
    const float* __restrict__ pw, __bf16* __restrict__ pwb) {
  const int bid = blockIdx.x;
  const int t   = threadIdx.x;
  if (bid < 4096) {
    __shared__ float tile[32][33];   // [c_local][n_local]
    const int nt = bid & 511, ct = (bid >> 9) & 1, b = bid >> 10;
    const int n0 = nt * 32, c0 = ct * 32;
    const int tx = t & 31, ty = t >> 5;
#pragma unroll
    for (int k = 0; k < 32; k += 8)
      tile[ty + k][tx] = x[((size_t)(b * C_ + c0 + ty + k)) * N_ + n0 + tx];
    __syncthreads();
    const int nl = t >> 3;           // 0..31 (n)
    const int cb = (t & 7) * 4;      // 0..28 (c)
    bf16x4 p;
#pragma unroll
    for (int i = 0; i < 4; ++i) p[i] = (__bf16)tile[cb + i][nl];
    *(bf16x4*)&xt[((size_t)(b * N_ + n0 + nl)) * C_ + c0 + cb] = p;
  } else if (bid < 4352) {
    if (bid == 4096) {
#pragma unroll
      for (int i = 0; i < RST_; ++i) statsR[i * 256 + t] = 0.f;
    }
    const int j = (bid - 4096) * 256 + t;
    const float* sc = scores + (size_t)j * K_;
    const int*   id = idxmat + (size_t)j * K_;
    float sv[K_]; int iv[K_];
#pragma unroll
    for (int k = 0; k < K_; ++k) { sv[k] = sc[k]; iv[k] = id[k]; }
    int* outp = sampled + (size_t)j * S_;
#pragma unroll
    for (int k = 0; k < K_; ++k) {
      const float sk = sv[k];
      int rank = 0;
#pragma unroll
      for (int m = 0; m < K_; ++m)
        rank += ((sv[m] > sk) || (sv[m] == sk && m < k)) ? 1 : 0;
      if (rank < S_) outp[rank] = iv[k];
    }
  } else {
    // pack pw (OUT,2C) f32 -> per-thread bf16 fragments [256][32]
    const int o  = 16 * (t >> 6) + (t & 15);
    const int kb = 8 * ((t >> 4) & 3);
    const float* src = pw + (size_t)o * CH_;
    __bf16* dst = pwb + t * 32;
#pragma unroll
    for (int ts = 0; ts < 2; ++ts)
#pragma unroll
      for (int i = 0; i < 8; ++i) {
        dst[ts * 8 + i]      = (__bf16)src[32 * ts + kb + i];        // d-part
        dst[16 + ts * 8 + i] = (__bf16)src[C_ + 32 * ts + kb + i];   // c-part
      }
  }
}

// ---------------- BN stats: MLP-forced gather, register accum, wave reduce ----------------
// statsR[rep][0:64)=sum_d [64:128)=sumsq_d [128:192)=sum_cen [192:256)=sumsq_cen
__global__ __launch_bounds__(256, 4) void k_stats(const __bf16* __restrict__ xt,
                                                  const int* __restrict__ sampled,
                                                  float* __restrict__ statsR) {
  const int t    = threadIdx.x;
  const int lane = t & 63;
  const int w    = t >> 6;
  const int r    = t >> 4;            // 0..15
  const int q    = t & 15;            // channel quad
  const int j0   = blockIdx.x * 32;
  const int jA   = j0 + r;
  const int jB   = j0 + 16 + r;

  int ia[S_], ib[S_];
  const int* spA = sampled + (size_t)jA * S_;
  const int* spB = sampled + (size_t)jB * S_;
#pragma unroll
  for (int s = 0; s < S_; ++s) { ia[s] = spA[s]; ib[s] = spB[s]; }

  u16x4 cA = *(const u16x4*)&xt[jA * C_ + 4 * q];
  u16x4 cB = *(const u16x4*)&xt[jB * C_ + 4 * q];

  u16x4 vA[S_], vB[S_];
#pragma unroll
  for (int s = 0; s < S_; ++s) {
    vA[s] = *(const u16x4*)&xt[ia[s] * C_ + 4 * q];
    vB[s] = *(const u16x4*)&xt[ib[s] * C_ + 4 * q];
  }
  __builtin_amdgcn_sched_barrier(0);   // all loads issued before any compute

  f32x4 sd = {0,0,0,0}, qd = {0,0,0,0}, sc = {0,0,0,0}, qc = {0,0,0,0};
  float cenA[4], cenB[4];
#pragma unroll
  for (int i = 0; i < 4; ++i) {
    cenA[i] = bf2f(cA[i]); cenB[i] = bf2f(cB[i]);
    sc[i] += cenA[i] + cenB[i];
    qc[i] += cenA[i] * cenA[i] + cenB[i] * cenB[i];
  }
#pragma unroll
  for (int s = 0; s < S_; ++s) {
#pragma unroll
    for (int i = 0; i < 4; ++i) {
      const float dA = bf2f(vA[s][i]) - cenA[i];
      const float dB = bf2f(vB[s][i]) - cenB[i];
      sd[i] += dA + dB;
      qd[i] += dA * dA + dB * dB;
    }
  }

#pragma unroll
  for (int i = 0; i < 4; ++i) {
    sd[i] += __shfl_xor(sd[i], 16); sd[i] += __shfl_xor(sd[i], 32);
    qd[i] += __shfl_xor(qd[i], 16); qd[i] += __shfl_xor(qd[i], 32);
    sc[i] += __shfl_xor(sc[i], 16); sc[i] += __shfl_xor(sc[i], 32);
    qc[i] += __shfl_xor(qc[i], 16); qc[i] += __shfl_xor(qc[i], 32);
  }

  __shared__ float sred[4][4][64];   // [stat][wave][channel]
  if (lane < 16) {
    *(f32x4*)&sred[0][w][4 * q] = sd;
    *(f32x4*)&sred[1][w][4 * q] = qd;
    *(f32x4*)&sred[2][w][4 * q] = sc;
    *(f32x4*)&sred[3][w][4 * q] = qc;
  }
  __syncthreads();
  if (t < 64) {
    float* dst = statsR + (blockIdx.x & (RST_ - 1)) * 256;
#pragma unroll
    for (int k = 0; k < 4; ++k) {
      const float v = sred[k][0][t] + sred[k][1][t] + sred[k][2][t] + sred[k][3][t];
      atomicAdd(&dst[k * 64 + t], v);
    }
  }
}

// ---------------- fold: replica-sum + BN fold -> AB[256] ----------------
__global__ void k_fold(const float* __restrict__ statsR, const float* __restrict__ dww,
                       const float* __restrict__ gamma, const float* __restrict__ beta,
                       float* __restrict__ AB) {
  __shared__ float sstat[256];
  const int t = threadIdx.x;   // 256 threads
  float sv = 0.f;
#pragma unroll
  for (int rr = 0; rr < RST_; ++rr) sv += statsR[rr * 256 + t];
  sstat[t] = sv;
  __syncthreads();
  if (t < CH_) {
    float mean_e, var_e;
    if (t < C_) {
      const float cnt = (float)ROWS_ * (float)S_;
      const float su = sstat[t], sq = sstat[64 + t];
      mean_e = su / cnt; var_e = sq / cnt - mean_e * mean_e;
    } else {
      const float cnt = (float)ROWS_;
      const float su = sstat[128 + (t - C_)], sq = sstat[192 + (t - C_)];
      mean_e = su / cnt; var_e = sq / cnt - mean_e * mean_e;
    }
    const float wg = dww[t], g = gamma[t];
    const float inv = rsqrtf(wg * wg * var_e + 1e-5f);
    AB[t]       = wg * g * inv;
    AB[CH_ + t] = beta[t] - wg * mean_e * inv * g;
  }
}

// ---------------- main: 32 rows/block, dual-tile MFMA, full gather preload ----------------
__global__ __launch_bounds__(256, 4) void k_main(
    const __bf16* __restrict__ xt, const int* __restrict__ sampled,
    const float* __restrict__ AB, const __bf16* __restrict__ pwb,
    float* __restrict__ out) {
  __shared__ __bf16 dact[160 * 64];   // 20480 B; rows (s*16+r), 128B each, XOR-swizzled
  __shared__ __bf16 cact[16 * 64];    //  2048 B
  float* ost = (float*)dact;          // epilogue alias: [32][68] = 8704 B (dact dead by then)

  const int t    = threadIdx.x;
  const int lane = t & 63;
  const int w    = t >> 6;            // wave -> output cols [16w,16w+16)
  const int j0   = blockIdx.x * 32;
  const int b    = j0 / N_;
  const int n0   = j0 % N_;
  const int r    = t >> 4;            // row 0..15 within tile
  const int q    = t & 15;            // channel quad
  const int jA   = j0 + r;
  const int jB   = j0 + 16 + r;

  // ---- load phase: everything in flight before any compute ----
  int ia[S_], ib[S_];
  const int* spA = sampled + (size_t)jA * S_;
  const int* spB = sampled + (size_t)jB * S_;
#pragma unroll
  for (int s = 0; s < S_; ++s) { ia[s] = spA[s]; ib[s] = spB[s]; }

  u16x4 cuA = *(const u16x4*)&xt[jA * C_ + 4 * q];
  u16x4 cuB = *(const u16x4*)&xt[jB * C_ + 4 * q];

  u16x4 vuA[S_], vuB[S_];
#pragma unroll
  for (int s = 0; s < S_; ++s) {
    vuA[s] = *(const u16x4*)&xt[ia[s] * C_ + 4 * q];
    vuB[s] = *(const u16x4*)&xt[ib[s] * C_ + 4 * q];
  }

  const f32x4 a_d = *(const f32x4*)&AB[4 * q];
  const f32x4 a_c = *(const f32x4*)&AB[C_ + 4 * q];
  const f32x4 b_d = *(const f32x4*)&AB[CH_ + 4 * q];
  const f32x4 b_c = *(const f32x4*)&AB[CH_ + C_ + 4 * q];

  bf16x8 bfd[2], bfc[2];
  {
    const bf16x8* fp = (const bf16x8*)(pwb + t * 32);
    bfd[0] = fp[0]; bfd[1] = fp[1]; bfc[0] = fp[2]; bfc[1] = fp[3];
  }
  __builtin_amdgcn_sched_barrier(0);

  const int wbyt  = r * 128 + ((8 * q) ^ ((r & 7) << 4));   // act write offset (row r)
  const int arow  = lane & 15;
  const int akoff = 16 * (lane >> 4);
  const int swz   = (arow & 7) << 4;

  // ================= tile A =================
  float cen[4];
  {
    bf16x4 p;
#pragma unroll
    for (int i = 0; i < 4; ++i) {
      cen[i] = bf2f(cuA[i]);
      const float tt = a_c[i] * cen[i] + b_c[i];
      p[i] = (__bf16)fmaxf(tt, 0.2f * tt);
    }
    *(bf16x4*)((char*)cact + wbyt) = p;
  }
#pragma unroll
  for (int s = 0; s < S_; ++s) {
    bf16x4 p;
#pragma unroll
    for (int i = 0; i < 4; ++i) {
      const float d  = bf2f(vuA[s][i]) - cen[i];
      const float tt = a_d[i] * d + b_d[i];
      p[i] = (__bf16)fmaxf(tt, 0.2f * tt);
    }
    *(bf16x4*)((char*)dact + s * 2048 + wbyt) = p;   // row s*16+r; (row&7)==(r&7)
  }
  __syncthreads();

  f32x4 caccA = {0.f, 0.f, 0.f, 0.f};
#pragma unroll
  for (int ts = 0; ts < 2; ++ts) {
    bf16x8 a = *(bf16x8*)((char*)cact + arow * 128 + ((64 * ts + akoff) ^ swz));
    caccA = __builtin_amdgcn_mfma_f32_16x16x32_bf16(a, bfc[ts], caccA, 0, 0, 0);
  }
  f32x4 rmaxA;
  rmaxA[0] = rmaxA[1] = rmaxA[2] = rmaxA[3] = -__builtin_inff();
#pragma unroll
  for (int s = 0; s < S_; ++s) {
    f32x4 acc = {0.f, 0.f, 0.f, 0.f};
#pragma unroll
    for (int ts = 0; ts < 2; ++ts) {
      bf16x8 a = *(bf16x8*)((char*)dact + s * 2048 + arow * 128 + ((64 * ts + akoff) ^ swz));
      acc = __builtin_amdgcn_mfma_f32_16x16x32_bf16(a, bfd[ts], acc, 0, 0, 0);
    }
#pragma unroll
    for (int i = 0; i < 4; ++i) rmaxA[i] = fmaxf(rmaxA[i], acc[i]);
  }
  __syncthreads();   // tile-A LDS consumed

  // ================= tile B =================
  {
    bf16x4 p;
#pragma unroll
    for (int i = 0; i < 4; ++i) {
      cen[i] = bf2f(cuB[i]);
      const float tt = a_c[i] * cen[i] + b_c[i];
      p[i] = (__bf16)fmaxf(tt, 0.2f * tt);
    }
    *(bf16x4*)((char*)cact + wbyt) = p;
  }
#pragma unroll
  for (int s = 0; s < S_; ++s) {
    bf16x4 p;
#pragma unroll
    for (int i = 0; i < 4; ++i) {
      const float d  = bf2f(vuB[s][i]) - cen[i];
      const float tt = a_d[i] * d + b_d[i];
      p[i] = (__bf16)fmaxf(tt, 0.2f * tt);
    }
    *(bf16x4*)((char*)dact + s * 2048 + wbyt) = p;
  }
  __syncthreads();

  f32x4 caccB = {0.f, 0.f, 0.f, 0.f};
#pragma unroll
  for (int ts = 0; ts < 2; ++ts) {
    bf16x8 a = *(bf16x8*)((char*)cact + arow * 128 + ((64 * ts + akoff) ^ swz));
    caccB = __builtin_amdgcn_mfma_f32_16x16x32_bf16(a, bfc[ts], caccB, 0, 0, 0);
  }
  f32x4 rmaxB;
  rmaxB[0] = rmaxB[1] = rmaxB[2] = rmaxB[3] = -__builtin_inff();
#pragma unroll
  for (int s = 0; s < S_; ++s) {
    f32x4 acc = {0.f, 0.f, 0.f, 0.f};
#pragma unroll
    for (int ts = 0; ts < 2; ++ts) {
      bf16x8 a = *(bf16x8*)((char*)dact + s * 2048 + arow * 128 + ((64 * ts + akoff) ^ swz));
      acc = __builtin_amdgcn_mfma_f32_16x16x32_bf16(a, bfd[ts], acc, 0, 0, 0);
    }
#pragma unroll
    for (int i = 0; i < 4; ++i) rmaxB[i] = fmaxf(rmaxB[i], acc[i]);
  }
  __syncthreads();   // dact fully dead; reuse as ost[32][68]

  // ---- epilogue: stage both tiles, store 128B runs per o-row ----
  {
    const int ol = lane & 15;
    const int rb = 4 * (lane >> 4);
#pragma unroll
    for (int i = 0; i < 4; ++i) {
      ost[(rb + i) * 68 + 16 * w + ol]      = rmaxA[i] + caccA[i];
      ost[(16 + rb + i) * 68 + 16 * w + ol] = rmaxB[i] + caccB[i];
    }
  }
  __syncthreads();
  {
    const int o  = t >> 2;
    const int sg = t & 3;
    f32x4 vA, vB;
#pragma unroll
    for (int i = 0; i < 4; ++i) {
      vA[i] = ost[(sg * 4 + i) * 68 + o];
      vB[i] = ost[(16 + sg * 4 + i) * 68 + o];
    }
    float* op = &out[((size_t)(b * OUT_ + o)) * N_ + n0];
    *(f32x4*)(op + sg * 4)      = vA;
    *(f32x4*)(op + 16 + sg * 4) = vB;
  }
}

extern "C" void kernel_launch(void* const* d_in, const int* in_sizes, int n_in,
                              void* d_out, int out_size, void* d_ws, size_t ws_size,
                              hipStream_t stream) {
  const float* x      = (const float*)d_in[0];
  const int*   cif    = (const int*)  d_in[1];
  const float* scores = (const float*)d_in[2];
  const float* dww    = (const float*)d_in[3];
  const float* pw     = (const float*)d_in[4];
  const float* gamma  = (const float*)d_in[5];
  const float* beta   = (const float*)d_in[6];
  float* out = (float*)d_out;

  char* ws = (char*)d_ws;
  __bf16* xt      = (__bf16*)(ws);                                  //  8,388,608 B
  int*    sampled = (int*)   (ws + 8388608);                        //  2,621,440 B
  float*  statsR  = (float*) (ws + 8388608 + 2621440);              //     16,384 B
  float*  AB      = (float*) (ws + 8388608 + 2621440 + 16384);      //      1,024 B
  __bf16* pwb     = (__bf16*)(ws + 8388608 + 2621440 + 16384 + 1024); //   16,384 B

  k_prep<<<4096 + 256 + 1, 256, 0, stream>>>(x, xt, scores, cif, sampled, statsR, pw, pwb);
  k_stats<<<ROWS_ / 32, 256, 0, stream>>>(xt, sampled, statsR);
  k_fold<<<1, 256, 0, stream>>>(statsR, dww, gamma, beta, AB);
  k_main<<<ROWS_ / 32, 256, 0, stream>>>(xt, sampled, AB, pwb, out);
}